// Round 3
// baseline (10.744 us; speedup 1.0000x reference)
//
#include <hip/hip_runtime.h>

// Goodwin-Lotka-Volterra Euler integration with policy intervention.
// Serial recurrence, one wave. Per-step instruction count minimized:
//   xy = x*y                       (1 VALU)
//   (xn,yn) = (a1,a2)*(x,y) + (-k1,k2)*xy   (packed mul + packed fma)
//   ds_write_b64 of raw (xn,yn)    (1 DS op; clamping deferred to writeout)
// Unclamped state propagates; clamped values are produced at writeout.

#define GV_LDS_CAP 1024

__global__ void goodwin_volterra_kernel(const float* __restrict__ ps_ptr,
                                        const int* __restrict__ steps_ptr,
                                        float* __restrict__ out) {
    __shared__ float2 buf[GV_LDS_CAP];

    const int tid   = threadIdx.x;
    const int steps = steps_ptr[0];
    const bool use_lds = (steps <= GV_LDS_CAP);

    if (tid == 0) {
        const float ps = fabsf(ps_ptr[0]);

        constexpr float ALPHA = 0.1f;
        constexpr float BETA  = 0.5f;
        constexpr float DELTA = 0.5f;
        constexpr float GAMMA = 0.2f;
        constexpr float DT    = 0.1f;

        // Folded coefficients: x_new = a1*x - k1*xy ; y_new = a2*y + k2*xy
        const float2 ca = {1.0f + ALPHA * DT, 1.0f - GAMMA * DT};
        const float2 ck = {-(DT * (BETA + ps)), DT * (DELTA + ps)};

        float2 s = {0.8f, 0.3f};

        if (use_lds) {
            #pragma unroll 4
            for (int i = 0; i < steps; ++i) {
                float xy = s.x * s.y;              // dep op 1
                float2 t;                          // retention terms (prev state)
                t.x = ca.x * s.x;
                t.y = ca.y * s.y;
                float2 sn;
                sn.x = fmaf(ck.x, xy, t.x);        // dep op 2 (packed-capable)
                sn.y = fmaf(ck.y, xy, t.y);
                buf[i] = sn;                       // raw values; clamp later
                s = sn;
            }
        } else {
            for (int i = 0; i < steps; ++i) {
                float xy = s.x * s.y;
                float2 sn;
                sn.x = fmaf(ck.x, xy, ca.x * s.x);
                sn.y = fmaf(ck.y, xy, ca.y * s.y);
                out[i]         = fminf(fmaxf(sn.x, 0.0f), 1.0f);
                out[steps + i] = fminf(fmaxf(sn.y, 0.0f), 1.0f);
                s = sn;
            }
        }
    }

    if (use_lds) {
        __syncthreads();
        for (int i = tid; i < steps; i += 64) {
            float2 v = buf[i];
            out[i]         = fminf(fmaxf(v.x, 0.0f), 1.0f);
            out[steps + i] = fminf(fmaxf(v.y, 0.0f), 1.0f);
        }
    }
}

extern "C" void kernel_launch(void* const* d_in, const int* in_sizes, int n_in,
                              void* d_out, int out_size, void* d_ws, size_t ws_size,
                              hipStream_t stream) {
    const float* ps    = (const float*)d_in[0];  // policy_strength, 1 elem f32
    const int*   steps = (const int*)d_in[1];    // steps, 1 elem i32
    float*       out   = (float*)d_out;          // [2*steps] f32: xs then ys

    goodwin_volterra_kernel<<<1, 64, 0, stream>>>(ps, steps, out);
}

// Round 4
// 9.357 us; speedup vs baseline: 1.1483x; 1.1483x over previous
//
#include <hip/hip_runtime.h>

// Goodwin-Lotka-Volterra Euler integration with policy intervention.
// Strictly serial recurrence (loop-carried dependency) -> one lane runs it.
// Folded update (BETA==DELTA==0.5 so one shared k):
//   xy = x*y
//   x_new = (1+ALPHA*DT)*x - k*xy
//   y_new = (1-GAMMA*DT)*y + k*xy,   k = DT*(0.5+|ps|)
// Unclamped state propagates; clamped values are recorded at writeout.
// steps==200 path is compile-time specialized: full unroll -> no loop
// overhead, LDS addresses folded to ds_write immediates / ds_write2 pairs.

#define GV_STEPS 200
#define GV_LDS_CAP 1024

__global__ void goodwin_volterra_kernel(const float* __restrict__ ps_ptr,
                                        const int* __restrict__ steps_ptr,
                                        float* __restrict__ out) {
    __shared__ float2 buf[GV_LDS_CAP];

    const int tid   = threadIdx.x;
    const int steps = steps_ptr[0];
    const bool fast = (steps == GV_STEPS);

    constexpr float ALPHA = 0.1f;
    constexpr float BETA  = 0.5f;
    constexpr float GAMMA = 0.2f;
    constexpr float DT    = 0.1f;

    if (tid == 0) {
        const float ps = fabsf(ps_ptr[0]);
        const float k  = DT * (BETA + ps);          // == DT*(DELTA+ps)
        const float ax = 1.0f + ALPHA * DT;         // x retention
        const float ay = 1.0f - GAMMA * DT;         // y retention

        float2 s = {0.8f, 0.3f};

        if (fast) {
            #pragma unroll
            for (int i = 0; i < GV_STEPS; ++i) {
                float xy = s.x * s.y;               // dep op 1
                float tx = ax * s.x;                // prev-state terms,
                float ty = ay * s.y;                //   off critical path
                s.x = fmaf(-k, xy, tx);             // dep op 2
                s.y = fmaf( k, xy, ty);
                buf[i] = s;                         // imm-offset ds_write
            }
        } else {
            for (int i = 0; i < steps; ++i) {
                float xy = s.x * s.y;
                float xn = fmaf(-k, xy, ax * s.x);
                float yn = fmaf( k, xy, ay * s.y);
                out[i]         = fminf(fmaxf(xn, 0.0f), 1.0f);
                out[steps + i] = fminf(fmaxf(yn, 0.0f), 1.0f);
                s.x = xn;
                s.y = yn;
            }
        }
    }

    if (fast) {
        __syncthreads();
        #pragma unroll
        for (int j = 0; j < (GV_STEPS + 63) / 64; ++j) {
            int i = tid + j * 64;
            if (i < GV_STEPS) {
                float2 v = buf[i];
                out[i]            = fminf(fmaxf(v.x, 0.0f), 1.0f);
                out[GV_STEPS + i] = fminf(fmaxf(v.y, 0.0f), 1.0f);
            }
        }
    }
}

extern "C" void kernel_launch(void* const* d_in, const int* in_sizes, int n_in,
                              void* d_out, int out_size, void* d_ws, size_t ws_size,
                              hipStream_t stream) {
    const float* ps    = (const float*)d_in[0];  // policy_strength, 1 elem f32
    const int*   steps = (const int*)d_in[1];    // steps, 1 elem i32
    float*       out   = (float*)d_out;          // [2*steps] f32: xs then ys

    goodwin_volterra_kernel<<<1, 64, 0, stream>>>(ps, steps, out);
}